// Round 5
// baseline (25882.806 us; speedup 1.0000x reference)
//
#include <hip/hip_runtime.h>
#include <float.h>

#define NB 64
#define HD 1024
#define H3 3072
#define NC6 6144
#define NV 32000
#define TSTEPS 32
#define LBK 1000        // logits blocks (32 cols each)
#define GKS 2           // gates K-split

__device__ __forceinline__ float sigmoidf_(float x) {
    return 1.0f / (1.0f + expf(-x));
}

__device__ __forceinline__ float dot4(float4 h, float4 w, float a) {
    return fmaf(h.w, w.w, fmaf(h.z, w.z, fmaf(h.y, w.y, fmaf(h.x, w.x, a))));
}

// ---- GEMV core: 8 cols/wave, lane = batch, K = NK16*16, reg ping-pong ----
// wb: W row base (col c0+r at wb + r*HD). t4: activations [kg][b] (base applied).
template<int NK16>
__device__ __forceinline__ void gemv8(const float* __restrict__ wb,
                                      const float4* __restrict__ t4,
                                      int lane, float* __restrict__ acc)
{
    float4 wA[8][2], wB[8][2], hA[2], hB[2];
    #pragma unroll
    for (int r = 0; r < 8; ++r) {
        wA[r][0] = *(const float4*)&wb[(size_t)r * HD + 0];
        wA[r][1] = *(const float4*)&wb[(size_t)r * HD + 4];
        wB[r][0] = *(const float4*)&wb[(size_t)r * HD + 8];
        wB[r][1] = *(const float4*)&wb[(size_t)r * HD + 12];
    }
    hA[0] = t4[0 * NB + lane]; hA[1] = t4[1 * NB + lane];
    hB[0] = t4[2 * NB + lane]; hB[1] = t4[3 * NB + lane];

    for (int it = 0; it < NK16 - 1; ++it) {
        const float*  wp = wb + (size_t)(it + 1) * 16;
        const float4* tp = t4 + (size_t)(it + 1) * 4 * NB;
        // compute A (k 0..7 of tile it), then refill A from tile it+1
        #pragma unroll
        for (int r = 0; r < 8; ++r)
            acc[r] = dot4(hA[1], wA[r][1], dot4(hA[0], wA[r][0], acc[r]));
        #pragma unroll
        for (int r = 0; r < 8; ++r) {
            wA[r][0] = *(const float4*)&wp[(size_t)r * HD + 0];
            wA[r][1] = *(const float4*)&wp[(size_t)r * HD + 4];
        }
        hA[0] = tp[lane]; hA[1] = tp[NB + lane];
        // compute B (k 8..15 of tile it), then refill B from tile it+1
        #pragma unroll
        for (int r = 0; r < 8; ++r)
            acc[r] = dot4(hB[1], wB[r][1], dot4(hB[0], wB[r][0], acc[r]));
        #pragma unroll
        for (int r = 0; r < 8; ++r) {
            wB[r][0] = *(const float4*)&wp[(size_t)r * HD + 8];
            wB[r][1] = *(const float4*)&wp[(size_t)r * HD + 12];
        }
        hB[0] = tp[2 * NB + lane]; hB[1] = tp[3 * NB + lane];
    }
    #pragma unroll
    for (int r = 0; r < 8; ++r)
        acc[r] = dot4(hA[1], wA[r][1], dot4(hA[0], wA[r][0], acc[r]));
    #pragma unroll
    for (int r = 0; r < 8; ++r)
        acc[r] = dot4(hB[1], wB[r][1], dot4(hB[0], wB[r][0], acc[r]));
}

// ---------------- init: ht4 = [zs|cs]^T, xt4 = emb[SOS=1]^T ----------------
__global__ __launch_bounds__(256) void init_kernel(
    const float* __restrict__ zs, const float* __restrict__ cs,
    const float* __restrict__ emb,
    float4* __restrict__ ht4, float4* __restrict__ xt4)
{
    int b = blockIdx.x;
    int kg = threadIdx.x;
    int j = kg * 4;
    float4 v;
    if (j < 512) v = *(const float4*)&zs[b * 512 + j];
    else         v = *(const float4*)&cs[b * 512 + (j - 512)];
    ht4[kg * NB + b] = v;
    xt4[kg * NB + b] = *(const float4*)&emb[HD + j];  // SOS = 1
}

// ---------------- logits GEMV + per-block argmax ----------------
// 1000 blocks x 256 thr; wave wid: cols blk*32 + wid*8 .. +7; lane = batch.
__global__ __launch_bounds__(256, 2) void logits_gemv(
    const float4* __restrict__ ht4, const float* __restrict__ Wout,
    const float* __restrict__ bout,
    float* __restrict__ bval, int* __restrict__ bidx)
{
    int tid = threadIdx.x, wid = tid >> 6, lane = tid & 63;
    int c0 = blockIdx.x * 32 + wid * 8;
    const float* __restrict__ wb = Wout + (size_t)c0 * HD;

    float acc[8] = {};
    gemv8<64>(wb, ht4, lane, acc);

    // per-lane argmax over 8 ascending cols (first-max tie-break)
    float bv = acc[0] + bout[c0];
    int   bi = c0;
    #pragma unroll
    for (int r = 1; r < 8; ++r) {
        float v = acc[r] + bout[c0 + r];
        if (v > bv) { bv = v; bi = c0 + r; }
    }
    __shared__ float sv[4][NB];
    __shared__ int   si[4][NB];
    sv[wid][lane] = bv;
    si[wid][lane] = bi;
    __syncthreads();
    if (wid == 0) {
        float v0 = sv[0][lane]; int i0 = si[0][lane];
        #pragma unroll
        for (int s = 1; s < 4; ++s) {
            float v = sv[s][lane];
            if (v > v0) { v0 = v; i0 = si[s][lane]; }   // slots ascend in col
        }
        bval[(size_t)lane * LBK + blockIdx.x] = v0;
        bidx[(size_t)lane * LBK + blockIdx.x] = i0;
    }
}

// ---------------- gates GEMV, K-split 2, gpart[ks][b][6144] ----------------
// 384 blocks: cg = blk>>1 (32 cols), ks = blk&1 (512-k slice).
__global__ __launch_bounds__(256, 2) void gates_gemv(
    const float4* __restrict__ xt4, const float4* __restrict__ ht4,
    const float* __restrict__ Wih, const float* __restrict__ Whh,
    float* __restrict__ gpart)
{
    int cg = blockIdx.x >> 1;
    int ks = blockIdx.x & 1;
    int tid = threadIdx.x, wid = tid >> 6, lane = tid & 63;
    int c0 = cg * 32 + wid * 8;            // 0..6143
    bool isH = c0 >= H3;
    const float4* __restrict__ T4 = (isH ? ht4 : xt4) + (size_t)ks * 128 * NB;
    const float* __restrict__ W   = isH ? Whh : Wih;
    const float* __restrict__ wb  = W + (size_t)(c0 - (isH ? H3 : 0)) * HD + ks * 512;

    float acc[8] = {};
    gemv8<32>(wb, T4, lane, acc);

    float* g = gpart + (size_t)(ks * NB + lane) * NC6 + c0;
    *(float4*)(g)     = make_float4(acc[0], acc[1], acc[2], acc[3]);
    *(float4*)(g + 4) = make_float4(acc[4], acc[5], acc[6], acc[7]);
}

// ---------------- GRU gate fusion: ht4 = (1-z)*n + z*ht4 ----------------
__global__ __launch_bounds__(256) void gru_fuse(
    const float* __restrict__ gpart,
    const float* __restrict__ bih, const float* __restrict__ bhh,
    float4* __restrict__ ht4)
{
    int b = blockIdx.x;
    int kg = threadIdx.x;
    int j0 = kg * 4;
    float4 ir = {}, iz = {}, in_ = {}, hr = {}, hz = {}, hn = {};
    #pragma unroll
    for (int ks = 0; ks < GKS; ++ks) {
        const float* g = gpart + (size_t)(ks * NB + b) * NC6;
        float4 a;
        a = *(const float4*)&g[j0];             ir.x+=a.x; ir.y+=a.y; ir.z+=a.z; ir.w+=a.w;
        a = *(const float4*)&g[HD + j0];        iz.x+=a.x; iz.y+=a.y; iz.z+=a.z; iz.w+=a.w;
        a = *(const float4*)&g[2*HD + j0];      in_.x+=a.x; in_.y+=a.y; in_.z+=a.z; in_.w+=a.w;
        a = *(const float4*)&g[H3 + j0];        hr.x+=a.x; hr.y+=a.y; hr.z+=a.z; hr.w+=a.w;
        a = *(const float4*)&g[H3 + HD + j0];   hz.x+=a.x; hz.y+=a.y; hz.z+=a.z; hz.w+=a.w;
        a = *(const float4*)&g[H3 + 2*HD + j0]; hn.x+=a.x; hn.y+=a.y; hn.z+=a.z; hn.w+=a.w;
    }
    float4 vbi0 = *(const float4*)&bih[j0];
    float4 vbi1 = *(const float4*)&bih[HD + j0];
    float4 vbi2 = *(const float4*)&bih[2*HD + j0];
    float4 vbh0 = *(const float4*)&bhh[j0];
    float4 vbh1 = *(const float4*)&bhh[HD + j0];
    float4 vbh2 = *(const float4*)&bhh[2*HD + j0];
    float4 hv = ht4[kg * NB + b];
    float irv[4] = {ir.x+vbi0.x, ir.y+vbi0.y, ir.z+vbi0.z, ir.w+vbi0.w};
    float izv[4] = {iz.x+vbi1.x, iz.y+vbi1.y, iz.z+vbi1.z, iz.w+vbi1.w};
    float inv[4] = {in_.x+vbi2.x, in_.y+vbi2.y, in_.z+vbi2.z, in_.w+vbi2.w};
    float hrv[4] = {hr.x+vbh0.x, hr.y+vbh0.y, hr.z+vbh0.z, hr.w+vbh0.w};
    float hzv[4] = {hz.x+vbh1.x, hz.y+vbh1.y, hz.z+vbh1.z, hz.w+vbh1.w};
    float hnv[4] = {hn.x+vbh2.x, hn.y+vbh2.y, hn.z+vbh2.z, hn.w+vbh2.w};
    float hvv[4] = {hv.x, hv.y, hv.z, hv.w};
    float o[4];
    #pragma unroll
    for (int u = 0; u < 4; ++u) {
        float r = sigmoidf_(irv[u] + hrv[u]);
        float z = sigmoidf_(izv[u] + hzv[u]);
        float n = tanhf(inv[u] + r * hnv[u]);
        o[u] = (1.0f - z) * n + z * hvv[u];
    }
    ht4[kg * NB + b] = make_float4(o[0], o[1], o[2], o[3]);
}

// ---------------- argmax reduce across 1000 blocks + embedding gather ----------------
__global__ __launch_bounds__(512) void argmax_reduce_gather(
    const float* __restrict__ bval, const int* __restrict__ bidx,
    const float* __restrict__ emb, int* __restrict__ resps, int t,
    float4* __restrict__ xt4)
{
    int b = blockIdx.x;
    int tid = threadIdx.x;
    float bv = bval[(size_t)b * LBK + tid];
    int   bi = bidx[(size_t)b * LBK + tid];
    int j = tid + 512;
    if (j < LBK) {
        float v2 = bval[(size_t)b * LBK + j];
        if (v2 > bv) { bv = v2; bi = bidx[(size_t)b * LBK + j]; }  // j > tid: keep first on tie
    }
    for (int off = 32; off > 0; off >>= 1) {
        float ov = __shfl_down(bv, off);
        int   oi = __shfl_down(bi, off);
        if (ov > bv || (ov == bv && oi < bi)) { bv = ov; bi = oi; }
    }
    __shared__ float sv[8];
    __shared__ int   si[8];
    __shared__ int   stok;
    int wid = tid >> 6;
    if ((tid & 63) == 0) { sv[wid] = bv; si[wid] = bi; }
    __syncthreads();
    if (tid == 0) {
        bv = sv[0]; bi = si[0];
        #pragma unroll
        for (int w = 1; w < 8; ++w)
            if (sv[w] > bv || (sv[w] == bv && si[w] < bi)) { bv = sv[w]; bi = si[w]; }
        stok = bi;
        resps[b * TSTEPS + t] = bi;
    }
    __syncthreads();
    if (tid < 256) {
        int tok = stok;
        xt4[tid * NB + b] = *(const float4*)&emb[(size_t)tok * HD + tid * 4];
    }
}

// ---------------- resp_lens ----------------
__global__ void resp_lens_kernel(const int* __restrict__ resps, int* __restrict__ lens)
{
    int b = threadIdx.x;
    if (b >= NB) return;
    int len = TSTEPS + 1;
    for (int t = TSTEPS - 1; t >= 0; t--)
        if (resps[b * TSTEPS + t] == 2) len = t + 1;
    lens[b] = len;
}

extern "C" void kernel_launch(void* const* d_in, const int* in_sizes, int n_in,
                              void* d_out, int out_size, void* d_ws, size_t ws_size,
                              hipStream_t stream) {
    const float* zs   = (const float*)d_in[0];
    const float* cs   = (const float*)d_in[1];
    const float* emb  = (const float*)d_in[2];
    const float* Wih  = (const float*)d_in[3];
    const float* Whh  = (const float*)d_in[4];
    const float* bih  = (const float*)d_in[5];
    const float* bhh  = (const float*)d_in[6];
    const float* Wout = (const float*)d_in[7];
    const float* bout = (const float*)d_in[8];
    int* out = (int*)d_out;  // [64*32 resps][64 lens], int32

    char* ws = (char*)d_ws;
    float4* xt4  = (float4*)ws; ws += (size_t)256 * NB * 16;          // 256 KB
    float4* ht4  = (float4*)ws; ws += (size_t)256 * NB * 16;          // 256 KB
    float*  gpart = (float*)ws; ws += (size_t)GKS * NB * NC6 * 4;     // 3.1 MB
    float*  bval = (float*)ws;  ws += (size_t)NB * LBK * 4;           // 256 KB
    int*    bidx = (int*)ws;    ws += (size_t)NB * LBK * 4;           // 256 KB

    init_kernel<<<NB, 256, 0, stream>>>(zs, cs, emb, ht4, xt4);
    for (int t = 0; t < TSTEPS; t++) {
        gates_gemv<<<192 * GKS, 256, 0, stream>>>(xt4, ht4, Wih, Whh, gpart);
        gru_fuse<<<NB, 256, 0, stream>>>(gpart, bih, bhh, ht4);
        logits_gemv<<<LBK, 256, 0, stream>>>(ht4, Wout, bout, bval, bidx);
        argmax_reduce_gather<<<NB, 512, 0, stream>>>(bval, bidx, emb, out, t, xt4);
    }
    resp_lens_kernel<<<1, 64, 0, stream>>>(out, out + NB * TSTEPS);
}

// Round 6
// 8584.611 us; speedup vs baseline: 3.0150x; 3.0150x over previous
//
#include <hip/hip_runtime.h>
#include <float.h>

#define NB 64
#define HD 1024
#define H3 3072
#define NC6 6144
#define NV 32000
#define TSTEPS 32
#define LBLK 500        // logits blocks (64 cols each)
#define GKS 4           // gates K-split

__device__ __forceinline__ float sigmoidf_(float x) {
    return 1.0f / (1.0f + expf(-x));
}

__device__ __forceinline__ float dot4(float4 h, float4 w, float a) {
    return fmaf(h.w, w.w, fmaf(h.z, w.z, fmaf(h.y, w.y, fmaf(h.x, w.x, a))));
}

// ---- GEMV core: lane (bl,ch) computes 8 cols x 2 batches (bl, bl+32) ----
// wb: W base for this lane's col block (col c0+r at wb + r*HD), k offset 0.
// t4: activations float4[kg][64] slice base. K = NPAIR*2 kg-groups (8*NPAIR k).
// Live set: wc 32 + wn 32 + h 16 + acc 16 VGPRs -> fits 128-cap, no spill.
template<int NPAIR>
__device__ __forceinline__ void gemv_core(const float* __restrict__ wb,
                                          const float4* __restrict__ t4,
                                          int bl, float acc0[8], float acc1[8])
{
    float4 wc[8], wn[8], h0c, h1c, h0n, h1n;
    #pragma unroll
    for (int r = 0; r < 8; ++r) wc[r] = *(const float4*)&wb[(size_t)r * HD];
    h0c = t4[bl]; h1c = t4[bl + 32];

    #pragma unroll 1
    for (int p = 0; p < NPAIR - 1; ++p) {
        const float*  w1 = wb + (2 * p + 1) * 4;
        const float4* t1 = t4 + (size_t)(2 * p + 1) * NB;
        #pragma unroll
        for (int r = 0; r < 8; ++r) wn[r] = *(const float4*)&w1[(size_t)r * HD];
        h0n = t1[bl]; h1n = t1[bl + 32];
        #pragma unroll
        for (int r = 0; r < 8; ++r) {
            acc0[r] = dot4(h0c, wc[r], acc0[r]);
            acc1[r] = dot4(h1c, wc[r], acc1[r]);
        }
        const float*  w2 = wb + (2 * p + 2) * 4;
        const float4* t2 = t4 + (size_t)(2 * p + 2) * NB;
        #pragma unroll
        for (int r = 0; r < 8; ++r) wc[r] = *(const float4*)&w2[(size_t)r * HD];
        h0c = t2[bl]; h1c = t2[bl + 32];
        #pragma unroll
        for (int r = 0; r < 8; ++r) {
            acc0[r] = dot4(h0n, wn[r], acc0[r]);
            acc1[r] = dot4(h1n, wn[r], acc1[r]);
        }
    }
    // last pair: kg = 2*NPAIR-2 (already in wc/h*c) and 2*NPAIR-1
    const float*  w1 = wb + (2 * NPAIR - 1) * 4;
    const float4* t1 = t4 + (size_t)(2 * NPAIR - 1) * NB;
    #pragma unroll
    for (int r = 0; r < 8; ++r) wn[r] = *(const float4*)&w1[(size_t)r * HD];
    h0n = t1[bl]; h1n = t1[bl + 32];
    #pragma unroll
    for (int r = 0; r < 8; ++r) {
        acc0[r] = dot4(h0c, wc[r], acc0[r]);
        acc1[r] = dot4(h1c, wc[r], acc1[r]);
    }
    #pragma unroll
    for (int r = 0; r < 8; ++r) {
        acc0[r] = dot4(h0n, wn[r], acc0[r]);
        acc1[r] = dot4(h1n, wn[r], acc1[r]);
    }
}

// ---------------- init: ht4 = [zs|cs]^T, xt4 = emb[SOS=1]^T ----------------
__global__ __launch_bounds__(256) void init_kernel(
    const float* __restrict__ zs, const float* __restrict__ cs,
    const float* __restrict__ emb,
    float4* __restrict__ ht4, float4* __restrict__ xt4)
{
    int b = blockIdx.x;
    int kg = threadIdx.x;
    int j = kg * 4;
    float4 v;
    if (j < 512) v = *(const float4*)&zs[b * 512 + j];
    else         v = *(const float4*)&cs[b * 512 + (j - 512)];
    ht4[kg * NB + b] = v;
    xt4[kg * NB + b] = *(const float4*)&emb[HD + j];  // SOS = 1
}

// ---------------- logits GEMV + per-block argmax ----------------
// 500 blocks x 256 thr; lane (bl,ch) of wave wid: cols blk*64+wid*16+ch*8 ..+7,
// batches bl and bl+32. W loads half-wave-uniform; H loads contiguous 512B.
__global__ __launch_bounds__(256, 4) void logits_gemv(
    const float4* __restrict__ ht4, const float* __restrict__ Wout,
    const float* __restrict__ bout,
    float* __restrict__ bval, int* __restrict__ bidx)
{
    int tid = threadIdx.x, wid = tid >> 6, lane = tid & 63;
    int bl = lane & 31, ch = lane >> 5;
    int c0 = blockIdx.x * 64 + wid * 16 + ch * 8;
    const float* __restrict__ wb = Wout + (size_t)c0 * HD;

    float acc0[8] = {}, acc1[8] = {};
    gemv_core<128>(wb, ht4, bl, acc0, acc1);

    // bias + per-lane argmax over 8 ascending cols (first-max tie-break)
    float bv0 = -FLT_MAX, bv1 = -FLT_MAX; int bi0 = 0, bi1 = 0;
    #pragma unroll
    for (int r = 0; r < 8; ++r) {
        float bo = bout[c0 + r];
        float v0 = acc0[r] + bo;
        float v1 = acc1[r] + bo;
        if (v0 > bv0) { bv0 = v0; bi0 = c0 + r; }
        if (v1 > bv1) { bv1 = v1; bi1 = c0 + r; }
    }
    __shared__ float sv[NB][8];
    __shared__ int   si[NB][8];
    int slot = wid * 2 + ch;           // slots ascend in col
    sv[bl][slot] = bv0;      si[bl][slot] = bi0;
    sv[bl + 32][slot] = bv1; si[bl + 32][slot] = bi1;
    __syncthreads();
    if (wid == 0) {
        float bv = sv[lane][0]; int bi = si[lane][0];
        #pragma unroll
        for (int s = 1; s < 8; ++s) {
            float v = sv[lane][s];
            if (v > bv) { bv = v; bi = si[lane][s]; }
        }
        bval[(size_t)lane * LBLK + blockIdx.x] = bv;
        bidx[(size_t)lane * LBLK + blockIdx.x] = bi;
    }
}

// ---------------- gates GEMV, K-split 4, gpart[ks][b][6144] ----------------
// 384 blocks: cg = blk>>2 (64 cols), ks = blk&3 (256-k slice).
__global__ __launch_bounds__(256, 4) void gates_gemv(
    const float4* __restrict__ xt4, const float4* __restrict__ ht4,
    const float* __restrict__ Wih, const float* __restrict__ Whh,
    float* __restrict__ gpart)
{
    int cg = blockIdx.x >> 2;
    int ks = blockIdx.x & 3;
    int tid = threadIdx.x, wid = tid >> 6, lane = tid & 63;
    int bl = lane & 31, ch = lane >> 5;
    int c0 = cg * 64 + wid * 16 + ch * 8;   // 0..6143 (block col range is 64-aligned)
    bool isH = c0 >= H3;
    const float4* __restrict__ t4 = (isH ? ht4 : xt4) + (size_t)ks * 64 * NB;
    const float* __restrict__ W   = isH ? Whh : Wih;
    const float* __restrict__ wb  = W + (size_t)(c0 - (isH ? H3 : 0)) * HD + ks * 256;

    float acc0[8] = {}, acc1[8] = {};
    gemv_core<32>(wb, t4, bl, acc0, acc1);

    float* g0 = gpart + (size_t)(ks * NB + bl) * NC6 + c0;
    float* g1 = gpart + (size_t)(ks * NB + bl + 32) * NC6 + c0;
    *(float4*)(g0)     = make_float4(acc0[0], acc0[1], acc0[2], acc0[3]);
    *(float4*)(g0 + 4) = make_float4(acc0[4], acc0[5], acc0[6], acc0[7]);
    *(float4*)(g1)     = make_float4(acc1[0], acc1[1], acc1[2], acc1[3]);
    *(float4*)(g1 + 4) = make_float4(acc1[4], acc1[5], acc1[6], acc1[7]);
}

// ---------------- GRU gate fusion: ht4 = (1-z)*n + z*ht4 ----------------
__global__ __launch_bounds__(256) void gru_fuse(
    const float* __restrict__ gpart,
    const float* __restrict__ bih, const float* __restrict__ bhh,
    float4* __restrict__ ht4)
{
    int b = blockIdx.x;
    int kg = threadIdx.x;
    int j0 = kg * 4;
    float4 ir = {}, iz = {}, in_ = {}, hr = {}, hz = {}, hn = {};
    #pragma unroll
    for (int ks = 0; ks < GKS; ++ks) {
        const float* g = gpart + (size_t)(ks * NB + b) * NC6;
        float4 a;
        a = *(const float4*)&g[j0];             ir.x+=a.x; ir.y+=a.y; ir.z+=a.z; ir.w+=a.w;
        a = *(const float4*)&g[HD + j0];        iz.x+=a.x; iz.y+=a.y; iz.z+=a.z; iz.w+=a.w;
        a = *(const float4*)&g[2*HD + j0];      in_.x+=a.x; in_.y+=a.y; in_.z+=a.z; in_.w+=a.w;
        a = *(const float4*)&g[H3 + j0];        hr.x+=a.x; hr.y+=a.y; hr.z+=a.z; hr.w+=a.w;
        a = *(const float4*)&g[H3 + HD + j0];   hz.x+=a.x; hz.y+=a.y; hz.z+=a.z; hz.w+=a.w;
        a = *(const float4*)&g[H3 + 2*HD + j0]; hn.x+=a.x; hn.y+=a.y; hn.z+=a.z; hn.w+=a.w;
    }
    float4 vbi0 = *(const float4*)&bih[j0];
    float4 vbi1 = *(const float4*)&bih[HD + j0];
    float4 vbi2 = *(const float4*)&bih[2*HD + j0];
    float4 vbh0 = *(const float4*)&bhh[j0];
    float4 vbh1 = *(const float4*)&bhh[HD + j0];
    float4 vbh2 = *(const float4*)&bhh[2*HD + j0];
    float4 hv = ht4[kg * NB + b];
    float irv[4] = {ir.x+vbi0.x, ir.y+vbi0.y, ir.z+vbi0.z, ir.w+vbi0.w};
    float izv[4] = {iz.x+vbi1.x, iz.y+vbi1.y, iz.z+vbi1.z, iz.w+vbi1.w};
    float inv[4] = {in_.x+vbi2.x, in_.y+vbi2.y, in_.z+vbi2.z, in_.w+vbi2.w};
    float hrv[4] = {hr.x+vbh0.x, hr.y+vbh0.y, hr.z+vbh0.z, hr.w+vbh0.w};
    float hzv[4] = {hz.x+vbh1.x, hz.y+vbh1.y, hz.z+vbh1.z, hz.w+vbh1.w};
    float hnv[4] = {hn.x+vbh2.x, hn.y+vbh2.y, hn.z+vbh2.z, hn.w+vbh2.w};
    float hvv[4] = {hv.x, hv.y, hv.z, hv.w};
    float o[4];
    #pragma unroll
    for (int u = 0; u < 4; ++u) {
        float r = sigmoidf_(irv[u] + hrv[u]);
        float z = sigmoidf_(izv[u] + hzv[u]);
        float n = tanhf(inv[u] + r * hnv[u]);
        o[u] = (1.0f - z) * n + z * hvv[u];
    }
    ht4[kg * NB + b] = make_float4(o[0], o[1], o[2], o[3]);
}

// ---------------- argmax reduce across 500 blocks + embedding gather ----------------
__global__ __launch_bounds__(512) void argmax_reduce_gather(
    const float* __restrict__ bval, const int* __restrict__ bidx,
    const float* __restrict__ emb, int* __restrict__ resps, int t,
    float4* __restrict__ xt4)
{
    int b = blockIdx.x;
    int tid = threadIdx.x;
    float bv = -FLT_MAX; int bi = 0x7fffffff;
    if (tid < LBLK) { bv = bval[(size_t)b * LBLK + tid]; bi = bidx[(size_t)b * LBLK + tid]; }
    for (int off = 32; off > 0; off >>= 1) {
        float ov = __shfl_down(bv, off);
        int   oi = __shfl_down(bi, off);
        if (ov > bv || (ov == bv && oi < bi)) { bv = ov; bi = oi; }
    }
    __shared__ float sv[8];
    __shared__ int   si[8];
    __shared__ int   stok;
    int wid = tid >> 6;
    if ((tid & 63) == 0) { sv[wid] = bv; si[wid] = bi; }
    __syncthreads();
    if (tid == 0) {
        bv = sv[0]; bi = si[0];
        #pragma unroll
        for (int w = 1; w < 8; ++w)
            if (sv[w] > bv || (sv[w] == bv && si[w] < bi)) { bv = sv[w]; bi = si[w]; }
        stok = bi;
        resps[b * TSTEPS + t] = bi;
    }
    __syncthreads();
    if (tid < 256) {
        int tok = stok;
        xt4[tid * NB + b] = *(const float4*)&emb[(size_t)tok * HD + tid * 4];
    }
}

// ---------------- resp_lens ----------------
__global__ void resp_lens_kernel(const int* __restrict__ resps, int* __restrict__ lens)
{
    int b = threadIdx.x;
    if (b >= NB) return;
    int len = TSTEPS + 1;
    for (int t = TSTEPS - 1; t >= 0; t--)
        if (resps[b * TSTEPS + t] == 2) len = t + 1;
    lens[b] = len;
}

extern "C" void kernel_launch(void* const* d_in, const int* in_sizes, int n_in,
                              void* d_out, int out_size, void* d_ws, size_t ws_size,
                              hipStream_t stream) {
    const float* zs   = (const float*)d_in[0];
    const float* cs   = (const float*)d_in[1];
    const float* emb  = (const float*)d_in[2];
    const float* Wih  = (const float*)d_in[3];
    const float* Whh  = (const float*)d_in[4];
    const float* bih  = (const float*)d_in[5];
    const float* bhh  = (const float*)d_in[6];
    const float* Wout = (const float*)d_in[7];
    const float* bout = (const float*)d_in[8];
    int* out = (int*)d_out;  // [64*32 resps][64 lens], int32

    char* ws = (char*)d_ws;
    float4* xt4  = (float4*)ws; ws += (size_t)256 * NB * 16;          // 256 KB
    float4* ht4  = (float4*)ws; ws += (size_t)256 * NB * 16;          // 256 KB
    float*  gpart = (float*)ws; ws += (size_t)GKS * NB * NC6 * 4;     // 6.3 MB
    float*  bval = (float*)ws;  ws += (size_t)NB * LBLK * 4;          // 128 KB
    int*    bidx = (int*)ws;    ws += (size_t)NB * LBLK * 4;          // 128 KB

    init_kernel<<<NB, 256, 0, stream>>>(zs, cs, emb, ht4, xt4);
    for (int t = 0; t < TSTEPS; t++) {
        gates_gemv<<<96 * GKS, 256, 0, stream>>>(xt4, ht4, Wih, Whh, gpart);
        gru_fuse<<<NB, 256, 0, stream>>>(gpart, bih, bhh, ht4);
        logits_gemv<<<LBLK, 256, 0, stream>>>(ht4, Wout, bout, bval, bidx);
        argmax_reduce_gather<<<NB, 512, 0, stream>>>(bval, bidx, emb, out, t, xt4);
    }
    resp_lens_kernel<<<1, 64, 0, stream>>>(out, out + NB * TSTEPS);
}

// Round 7
// 7361.680 us; speedup vs baseline: 3.5159x; 1.1661x over previous
//
#include <hip/hip_runtime.h>
#include <float.h>

#define NB 64
#define HD 1024
#define H3 3072
#define NC6 6144
#define NV 32000
#define TSTEPS 32
#define LBLK 500        // logits blocks (64 cols each)
#define GKS 4           // gates K-split

__device__ __forceinline__ float sigmoidf_(float x) {
    return 1.0f / (1.0f + expf(-x));
}

__device__ __forceinline__ float dot4(float4 h, float4 w, float a) {
    return fmaf(h.w, w.w, fmaf(h.z, w.z, fmaf(h.y, w.y, fmaf(h.x, w.x, a))));
}

// ---- GEMV core: lane (bl,ch) computes 8 cols x 2 batches (bl, bl+32) ----
// wb: W base for this lane's col block (col c0+r at wb + r*HD), k offset 0.
// t4: activations float4[kg][64] slice base. K = NPAIR*2 kg-groups (8*NPAIR k).
// Live set: wc 32 + wn 32 + h 16 + acc 16 + addr ~115 VGPRs -> needs >=128 cap.
template<int NPAIR>
__device__ __forceinline__ void gemv_core(const float* __restrict__ wb,
                                          const float4* __restrict__ t4,
                                          int bl, float acc0[8], float acc1[8])
{
    float4 wc[8], wn[8], h0c, h1c, h0n, h1n;
    #pragma unroll
    for (int r = 0; r < 8; ++r) wc[r] = *(const float4*)&wb[(size_t)r * HD];
    h0c = t4[bl]; h1c = t4[bl + 32];

    #pragma unroll 1
    for (int p = 0; p < NPAIR - 1; ++p) {
        const float*  w1 = wb + (2 * p + 1) * 4;
        const float4* t1 = t4 + (size_t)(2 * p + 1) * NB;
        #pragma unroll
        for (int r = 0; r < 8; ++r) wn[r] = *(const float4*)&w1[(size_t)r * HD];
        h0n = t1[bl]; h1n = t1[bl + 32];
        #pragma unroll
        for (int r = 0; r < 8; ++r) {
            acc0[r] = dot4(h0c, wc[r], acc0[r]);
            acc1[r] = dot4(h1c, wc[r], acc1[r]);
        }
        const float*  w2 = wb + (2 * p + 2) * 4;
        const float4* t2 = t4 + (size_t)(2 * p + 2) * NB;
        #pragma unroll
        for (int r = 0; r < 8; ++r) wc[r] = *(const float4*)&w2[(size_t)r * HD];
        h0c = t2[bl]; h1c = t2[bl + 32];
        #pragma unroll
        for (int r = 0; r < 8; ++r) {
            acc0[r] = dot4(h0n, wn[r], acc0[r]);
            acc1[r] = dot4(h1n, wn[r], acc1[r]);
        }
    }
    // last pair: kg = 2*NPAIR-2 (already in wc/h*c) and 2*NPAIR-1
    const float*  w1 = wb + (2 * NPAIR - 1) * 4;
    const float4* t1 = t4 + (size_t)(2 * NPAIR - 1) * NB;
    #pragma unroll
    for (int r = 0; r < 8; ++r) wn[r] = *(const float4*)&w1[(size_t)r * HD];
    h0n = t1[bl]; h1n = t1[bl + 32];
    #pragma unroll
    for (int r = 0; r < 8; ++r) {
        acc0[r] = dot4(h0c, wc[r], acc0[r]);
        acc1[r] = dot4(h1c, wc[r], acc1[r]);
    }
    #pragma unroll
    for (int r = 0; r < 8; ++r) {
        acc0[r] = dot4(h0n, wn[r], acc0[r]);
        acc1[r] = dot4(h1n, wn[r], acc1[r]);
    }
}

// ---------------- init: ht4 = [zs|cs]^T, xt4 = emb[SOS=1]^T ----------------
__global__ __launch_bounds__(256) void init_kernel(
    const float* __restrict__ zs, const float* __restrict__ cs,
    const float* __restrict__ emb,
    float4* __restrict__ ht4, float4* __restrict__ xt4)
{
    int b = blockIdx.x;
    int kg = threadIdx.x;
    int j = kg * 4;
    float4 v;
    if (j < 512) v = *(const float4*)&zs[b * 512 + j];
    else         v = *(const float4*)&cs[b * 512 + (j - 512)];
    ht4[kg * NB + b] = v;
    xt4[kg * NB + b] = *(const float4*)&emb[HD + j];  // SOS = 1
}

// ---------------- logits GEMV + per-block argmax ----------------
// 500 blocks x 256 thr; lane (bl,ch) of wave wid: cols blk*64+wid*16+ch*8 ..+7,
// batches bl and bl+32. W loads half-wave-uniform; H loads contiguous 512B.
// NOTE: no min-waves in launch_bounds — R5/R6 showed any cap below the ~115-reg
// live set forces scratch spills (WRITE_SIZE 59-186 MB/dispatch).
__global__ __launch_bounds__(256) void logits_gemv(
    const float4* __restrict__ ht4, const float* __restrict__ Wout,
    const float* __restrict__ bout,
    float* __restrict__ bval, int* __restrict__ bidx)
{
    int tid = threadIdx.x, wid = tid >> 6, lane = tid & 63;
    int bl = lane & 31, ch = lane >> 5;
    int c0 = blockIdx.x * 64 + wid * 16 + ch * 8;
    const float* __restrict__ wb = Wout + (size_t)c0 * HD;

    float acc0[8] = {}, acc1[8] = {};
    gemv_core<128>(wb, ht4, bl, acc0, acc1);

    // bias + per-lane argmax over 8 ascending cols (first-max tie-break)
    float bv0 = -FLT_MAX, bv1 = -FLT_MAX; int bi0 = 0, bi1 = 0;
    #pragma unroll
    for (int r = 0; r < 8; ++r) {
        float bo = bout[c0 + r];
        float v0 = acc0[r] + bo;
        float v1 = acc1[r] + bo;
        if (v0 > bv0) { bv0 = v0; bi0 = c0 + r; }
        if (v1 > bv1) { bv1 = v1; bi1 = c0 + r; }
    }
    __shared__ float sv[NB][8];
    __shared__ int   si[NB][8];
    int slot = wid * 2 + ch;           // slots ascend in col
    sv[bl][slot] = bv0;      si[bl][slot] = bi0;
    sv[bl + 32][slot] = bv1; si[bl + 32][slot] = bi1;
    __syncthreads();
    if (wid == 0) {
        float bv = sv[lane][0]; int bi = si[lane][0];
        #pragma unroll
        for (int s = 1; s < 8; ++s) {
            float v = sv[lane][s];
            if (v > bv) { bv = v; bi = si[lane][s]; }
        }
        bval[(size_t)lane * LBLK + blockIdx.x] = bv;
        bidx[(size_t)lane * LBLK + blockIdx.x] = bi;
    }
}

// ---------------- gates GEMV, K-split 4, gpart[ks][b][6144] ----------------
// 384 blocks: cg = blk>>2 (64 cols), ks = blk&3 (256-k slice).
__global__ __launch_bounds__(256) void gates_gemv(
    const float4* __restrict__ xt4, const float4* __restrict__ ht4,
    const float* __restrict__ Wih, const float* __restrict__ Whh,
    float* __restrict__ gpart)
{
    int cg = blockIdx.x >> 2;
    int ks = blockIdx.x & 3;
    int tid = threadIdx.x, wid = tid >> 6, lane = tid & 63;
    int bl = lane & 31, ch = lane >> 5;
    int c0 = cg * 64 + wid * 16 + ch * 8;   // 0..6143 (block col range is 64-aligned)
    bool isH = c0 >= H3;
    const float4* __restrict__ t4 = (isH ? ht4 : xt4) + (size_t)ks * 64 * NB;
    const float* __restrict__ W   = isH ? Whh : Wih;
    const float* __restrict__ wb  = W + (size_t)(c0 - (isH ? H3 : 0)) * HD + ks * 256;

    float acc0[8] = {}, acc1[8] = {};
    gemv_core<32>(wb, t4, bl, acc0, acc1);

    float* g0 = gpart + (size_t)(ks * NB + bl) * NC6 + c0;
    float* g1 = gpart + (size_t)(ks * NB + bl + 32) * NC6 + c0;
    *(float4*)(g0)     = make_float4(acc0[0], acc0[1], acc0[2], acc0[3]);
    *(float4*)(g0 + 4) = make_float4(acc0[4], acc0[5], acc0[6], acc0[7]);
    *(float4*)(g1)     = make_float4(acc1[0], acc1[1], acc1[2], acc1[3]);
    *(float4*)(g1 + 4) = make_float4(acc1[4], acc1[5], acc1[6], acc1[7]);
}

// ---------------- GRU gate fusion: ht4 = (1-z)*n + z*ht4 ----------------
__global__ __launch_bounds__(256) void gru_fuse(
    const float* __restrict__ gpart,
    const float* __restrict__ bih, const float* __restrict__ bhh,
    float4* __restrict__ ht4)
{
    int b = blockIdx.x;
    int kg = threadIdx.x;
    int j0 = kg * 4;
    float4 ir = {}, iz = {}, in_ = {}, hr = {}, hz = {}, hn = {};
    #pragma unroll
    for (int ks = 0; ks < GKS; ++ks) {
        const float* g = gpart + (size_t)(ks * NB + b) * NC6;
        float4 a;
        a = *(const float4*)&g[j0];             ir.x+=a.x; ir.y+=a.y; ir.z+=a.z; ir.w+=a.w;
        a = *(const float4*)&g[HD + j0];        iz.x+=a.x; iz.y+=a.y; iz.z+=a.z; iz.w+=a.w;
        a = *(const float4*)&g[2*HD + j0];      in_.x+=a.x; in_.y+=a.y; in_.z+=a.z; in_.w+=a.w;
        a = *(const float4*)&g[H3 + j0];        hr.x+=a.x; hr.y+=a.y; hr.z+=a.z; hr.w+=a.w;
        a = *(const float4*)&g[H3 + HD + j0];   hz.x+=a.x; hz.y+=a.y; hz.z+=a.z; hz.w+=a.w;
        a = *(const float4*)&g[H3 + 2*HD + j0]; hn.x+=a.x; hn.y+=a.y; hn.z+=a.z; hn.w+=a.w;
    }
    float4 vbi0 = *(const float4*)&bih[j0];
    float4 vbi1 = *(const float4*)&bih[HD + j0];
    float4 vbi2 = *(const float4*)&bih[2*HD + j0];
    float4 vbh0 = *(const float4*)&bhh[j0];
    float4 vbh1 = *(const float4*)&bhh[HD + j0];
    float4 vbh2 = *(const float4*)&bhh[2*HD + j0];
    float4 hv = ht4[kg * NB + b];
    float irv[4] = {ir.x+vbi0.x, ir.y+vbi0.y, ir.z+vbi0.z, ir.w+vbi0.w};
    float izv[4] = {iz.x+vbi1.x, iz.y+vbi1.y, iz.z+vbi1.z, iz.w+vbi1.w};
    float inv[4] = {in_.x+vbi2.x, in_.y+vbi2.y, in_.z+vbi2.z, in_.w+vbi2.w};
    float hrv[4] = {hr.x+vbh0.x, hr.y+vbh0.y, hr.z+vbh0.z, hr.w+vbh0.w};
    float hzv[4] = {hz.x+vbh1.x, hz.y+vbh1.y, hz.z+vbh1.z, hz.w+vbh1.w};
    float hnv[4] = {hn.x+vbh2.x, hn.y+vbh2.y, hn.z+vbh2.z, hn.w+vbh2.w};
    float hvv[4] = {hv.x, hv.y, hv.z, hv.w};
    float o[4];
    #pragma unroll
    for (int u = 0; u < 4; ++u) {
        float r = sigmoidf_(irv[u] + hrv[u]);
        float z = sigmoidf_(izv[u] + hzv[u]);
        float n = tanhf(inv[u] + r * hnv[u]);
        o[u] = (1.0f - z) * n + z * hvv[u];
    }
    ht4[kg * NB + b] = make_float4(o[0], o[1], o[2], o[3]);
}

// ---------------- argmax reduce across 500 blocks + embedding gather ----------------
__global__ __launch_bounds__(512) void argmax_reduce_gather(
    const float* __restrict__ bval, const int* __restrict__ bidx,
    const float* __restrict__ emb, int* __restrict__ resps, int t,
    float4* __restrict__ xt4)
{
    int b = blockIdx.x;
    int tid = threadIdx.x;
    float bv = -FLT_MAX; int bi = 0x7fffffff;
    if (tid < LBLK) { bv = bval[(size_t)b * LBLK + tid]; bi = bidx[(size_t)b * LBLK + tid]; }
    for (int off = 32; off > 0; off >>= 1) {
        float ov = __shfl_down(bv, off);
        int   oi = __shfl_down(bi, off);
        if (ov > bv || (ov == bv && oi < bi)) { bv = ov; bi = oi; }
    }
    __shared__ float sv[8];
    __shared__ int   si[8];
    __shared__ int   stok;
    int wid = tid >> 6;
    if ((tid & 63) == 0) { sv[wid] = bv; si[wid] = bi; }
    __syncthreads();
    if (tid == 0) {
        bv = sv[0]; bi = si[0];
        #pragma unroll
        for (int w = 1; w < 8; ++w)
            if (sv[w] > bv || (sv[w] == bv && si[w] < bi)) { bv = sv[w]; bi = si[w]; }
        stok = bi;
        resps[b * TSTEPS + t] = bi;
    }
    __syncthreads();
    if (tid < 256) {
        int tok = stok;
        xt4[tid * NB + b] = *(const float4*)&emb[(size_t)tok * HD + tid * 4];
    }
}

// ---------------- resp_lens ----------------
__global__ void resp_lens_kernel(const int* __restrict__ resps, int* __restrict__ lens)
{
    int b = threadIdx.x;
    if (b >= NB) return;
    int len = TSTEPS + 1;
    for (int t = TSTEPS - 1; t >= 0; t--)
        if (resps[b * TSTEPS + t] == 2) len = t + 1;
    lens[b] = len;
}

extern "C" void kernel_launch(void* const* d_in, const int* in_sizes, int n_in,
                              void* d_out, int out_size, void* d_ws, size_t ws_size,
                              hipStream_t stream) {
    const float* zs   = (const float*)d_in[0];
    const float* cs   = (const float*)d_in[1];
    const float* emb  = (const float*)d_in[2];
    const float* Wih  = (const float*)d_in[3];
    const float* Whh  = (const float*)d_in[4];
    const float* bih  = (const float*)d_in[5];
    const float* bhh  = (const float*)d_in[6];
    const float* Wout = (const float*)d_in[7];
    const float* bout = (const float*)d_in[8];
    int* out = (int*)d_out;  // [64*32 resps][64 lens], int32

    char* ws = (char*)d_ws;
    float4* xt4  = (float4*)ws; ws += (size_t)256 * NB * 16;          // 256 KB
    float4* ht4  = (float4*)ws; ws += (size_t)256 * NB * 16;          // 256 KB
    float*  gpart = (float*)ws; ws += (size_t)GKS * NB * NC6 * 4;     // 6.3 MB
    float*  bval = (float*)ws;  ws += (size_t)NB * LBLK * 4;          // 128 KB
    int*    bidx = (int*)ws;    ws += (size_t)NB * LBLK * 4;          // 128 KB

    init_kernel<<<NB, 256, 0, stream>>>(zs, cs, emb, ht4, xt4);
    for (int t = 0; t < TSTEPS; t++) {
        gates_gemv<<<96 * GKS, 256, 0, stream>>>(xt4, ht4, Wih, Whh, gpart);
        gru_fuse<<<NB, 256, 0, stream>>>(gpart, bih, bhh, ht4);
        logits_gemv<<<LBLK, 256, 0, stream>>>(ht4, Wout, bout, bval, bidx);
        argmax_reduce_gather<<<NB, 512, 0, stream>>>(bval, bidx, emb, out, t, xt4);
    }
    resp_lens_kernel<<<1, 64, 0, stream>>>(out, out + NB * TSTEPS);
}

// Round 10
// 5386.593 us; speedup vs baseline: 4.8050x; 1.3667x over previous
//
#include <hip/hip_runtime.h>
#include <hip/hip_bf16.h>
#include <float.h>

#define NB 64
#define HD 1024
#define H3 3072
#define NC6 6144
#define NV 32000
#define TSTEPS 32
#define LBLK 500        // logits blocks (64 cols each)
#define GKS 4           // gates K-split
#define NKT 16          // K=1024 / 64 per staging step
#define MARGIN_COEF 0.010f
#define MARGIN_ABS  1e-3f
#define MAXCAND 2048

using bf16x8 = __attribute__((ext_vector_type(8))) short;
using f32x4  = __attribute__((ext_vector_type(4))) float;
using s16x4  = __attribute__((ext_vector_type(4))) short;

__device__ __forceinline__ float sigmoidf_(float x) {
    return 1.0f / (1.0f + expf(-x));
}
__device__ __forceinline__ float dot4(float4 h, float4 w, float a) {
    return fmaf(h.w, w.w, fmaf(h.z, w.z, fmaf(h.y, w.y, fmaf(h.x, w.x, a))));
}
__device__ __forceinline__ short bf16bits(float x) {
    __hip_bfloat16 b = __float2bfloat16(x);
    return __builtin_bit_cast(short, b);
}

// ---------------- one-time: Wout -> Wbf (bf16) + wnorm ----------------
__global__ __launch_bounds__(256) void wbf_kernel(const float* __restrict__ W,
                                                  short* __restrict__ Wbf,
                                                  float* __restrict__ wnorm)
{
    int r = blockIdx.x, tdx = threadIdx.x;
    float4 v = *(const float4*)&W[(size_t)r * HD + tdx * 4];
    s16x4 p;
    p[0] = bf16bits(v.x); p[1] = bf16bits(v.y);
    p[2] = bf16bits(v.z); p[3] = bf16bits(v.w);
    *(s16x4*)(Wbf + (size_t)r * HD + tdx * 4) = p;
    float ss = v.x*v.x + v.y*v.y + v.z*v.z + v.w*v.w;
    #pragma unroll
    for (int off = 32; off; off >>= 1) ss += __shfl_xor(ss, off);
    __shared__ float red[4];
    if ((tdx & 63) == 0) red[tdx >> 6] = ss;
    __syncthreads();
    if (tdx == 0) wnorm[r] = sqrtf(red[0] + red[1] + red[2] + red[3]);
}

// ---------------- per-step: ht4 -> Abf (bf16 row-major) + hnorm ----------------
__global__ __launch_bounds__(256) void habf_kernel(const float4* __restrict__ ht4,
                                                   short* __restrict__ Abf,
                                                   float* __restrict__ hnorm)
{
    int b = blockIdx.x, kg = threadIdx.x;
    float4 v = ht4[kg * NB + b];
    s16x4 p;
    p[0] = bf16bits(v.x); p[1] = bf16bits(v.y);
    p[2] = bf16bits(v.z); p[3] = bf16bits(v.w);
    *(s16x4*)(Abf + (size_t)b * HD + kg * 4) = p;
    float ss = v.x*v.x + v.y*v.y + v.z*v.z + v.w*v.w;
    #pragma unroll
    for (int off = 32; off; off >>= 1) ss += __shfl_xor(ss, off);
    __shared__ float red[4];
    if ((kg & 63) == 0) red[kg >> 6] = ss;
    __syncthreads();
    if (kg == 0) hnorm[b] = sqrtf(red[0] + red[1] + red[2] + red[3]);
}

// ---------------- init: ht4 = [zs|cs]^T, xt4 = emb[SOS=1]^T ----------------
__global__ __launch_bounds__(256) void init_kernel(
    const float* __restrict__ zs, const float* __restrict__ cs,
    const float* __restrict__ emb,
    float4* __restrict__ ht4, float4* __restrict__ xt4)
{
    int b = blockIdx.x;
    int kg = threadIdx.x;
    int j = kg * 4;
    float4 v;
    if (j < 512) v = *(const float4*)&zs[b * 512 + j];
    else         v = *(const float4*)&cs[b * 512 + (j - 512)];
    ht4[kg * NB + b] = v;
    xt4[kg * NB + b] = *(const float4*)&emb[HD + j];  // SOS = 1
}

// ---------------- logits screen: bf16 MFMA GEMM -> lb[64][32000] ----------------
// 500 blocks x 256 thr (4 waves). Tile 64 batch x 64 cols, K=1024.
// LDS: 128 rows (0-63 A batches, 64-127 W cols) x 128 B, XOR-swizzled.
__global__ __launch_bounds__(256, 2) void logits_lb(
    const short* __restrict__ Abf, const short* __restrict__ Wbf,
    const float* __restrict__ bout, float* __restrict__ lb)
{
    __shared__ __align__(16) char tile[2][16384];

    const int tid = threadIdx.x;
    const int wv = tid >> 6, l = tid & 63;
    const int blk = blockIdx.x;

    // staging map: slot = i*256+tid -> row = slot>>3, kb = (slot&7)*16 bytes
    const short* srows[4];
    int lof[4];
    #pragma unroll
    for (int i = 0; i < 4; ++i) {
        int slot = i * 256 + tid;
        int row = slot >> 3;
        int kb  = (slot & 7) * 16;
        const short* g = (row < 64)
            ? (Abf + (size_t)row * HD)
            : (Wbf + ((size_t)(blk * 64 + (row - 64))) * HD);
        srows[i] = g + (kb >> 1);
        lof[i] = row * 128 + (kb ^ ((row & 7) << 4));
    }

    // fragment offsets: lane l -> index l&15, k-chunk (l>>4)*8 within kf half
    int a_off[4][2], b_off[2];
    #pragma unroll
    for (int m = 0; m < 4; ++m)
        #pragma unroll
        for (int kf = 0; kf < 2; ++kf) {
            int row = m * 16 + (l & 15);
            int kb = kf * 64 + (l >> 4) * 16;
            a_off[m][kf] = row * 128 + (kb ^ ((row & 7) << 4));
        }
    #pragma unroll
    for (int kf = 0; kf < 2; ++kf) {
        int row = 64 + wv * 16 + (l & 15);
        int kb = kf * 64 + (l >> 4) * 16;
        b_off[kf] = row * 128 + (kb ^ ((row & 7) << 4));
    }

    float4 rg[4];
    #pragma unroll
    for (int i = 0; i < 4; ++i) rg[i] = *(const float4*)(srows[i]);

    f32x4 acc[4] = {};

    int cur = 0;
    #pragma unroll 1
    for (int kt = 0; kt < NKT; ++kt) {
        char* buf = tile[cur];
        #pragma unroll
        for (int i = 0; i < 4; ++i) *(float4*)(buf + lof[i]) = rg[i];
        __syncthreads();
        if (kt < NKT - 1) {
            #pragma unroll
            for (int i = 0; i < 4; ++i)
                rg[i] = *(const float4*)(srows[i] + (size_t)(kt + 1) * 64);
        }
        #pragma unroll
        for (int kf = 0; kf < 2; ++kf) {
            bf16x8 bfrag = *(const bf16x8*)(buf + b_off[kf]);
            #pragma unroll
            for (int m = 0; m < 4; ++m) {
                bf16x8 afrag = *(const bf16x8*)(buf + a_off[m][kf]);
                acc[m] = __builtin_amdgcn_mfma_f32_16x16x32_bf16(afrag, bfrag, acc[m], 0, 0, 0);
            }
        }
        cur ^= 1;
        __syncthreads();
    }

    // D layout: col = l&15, row = m*16 + (l>>4)*4 + j  (verified mapping)
    int col = blk * 64 + wv * 16 + (l & 15);
    float bo = bout[col];
    #pragma unroll
    for (int m = 0; m < 4; ++m) {
        #pragma unroll
        for (int j = 0; j < 4; ++j) {
            int row = m * 16 + (l >> 4) * 4 + j;
            lb[(size_t)row * NV + col] = acc[m][j] + bo;
        }
    }
}

// ---------------- select candidates (rigorous margin) + exact fp32 rescore ----------------
// grid 64 (batch), 256 thr. margin m_c = MARGIN_COEF*|h|*|w_c| + MARGIN_ABS.
__global__ __launch_bounds__(256) void select_rescore(
    const float* __restrict__ lb, const float* __restrict__ wnorm,
    const float* __restrict__ hnorm,
    const float* __restrict__ Wout, const float* __restrict__ bout,
    const float4* __restrict__ ht4, const float* __restrict__ emb,
    int* __restrict__ resps, int t, float4* __restrict__ xt4)
{
    int b = blockIdx.x, tid = threadIdx.x, wv = tid >> 6;
    const float* lbr = lb + (size_t)b * NV;
    float coef = MARGIN_COEF * hnorm[b];

    // pass A: T = max_c (lb_c - m_c)
    float tmax = -FLT_MAX;
    for (int c = tid; c < NV; c += 256)
        tmax = fmaxf(tmax, lbr[c] - (coef * wnorm[c] + MARGIN_ABS));
    #pragma unroll
    for (int off = 32; off; off >>= 1) tmax = fmaxf(tmax, __shfl_xor(tmax, off));
    __shared__ float rmax[4];
    if ((tid & 63) == 0) rmax[wv] = tmax;
    __syncthreads();
    tmax = fmaxf(fmaxf(rmax[0], rmax[1]), fmaxf(rmax[2], rmax[3]));

    // pass B: collect {c : lb_c + m_c >= T}  (provably contains true argmax)
    __shared__ int scount;
    __shared__ int cand[MAXCAND];
    if (tid == 0) scount = 0;
    __syncthreads();
    for (int c = tid; c < NV; c += 256) {
        if (lbr[c] + (coef * wnorm[c] + MARGIN_ABS) >= tmax) {
            int s = atomicAdd(&scount, 1);
            if (s < MAXCAND) cand[s] = c;
        }
    }
    __syncthreads();
    int n = scount < MAXCAND ? scount : MAXCAND;

    // rescore candidates in exact fp32; first-index tie-break (order-invariant)
    float4 h4 = ht4[tid * NB + b];
    float best = -FLT_MAX; int bestc = 0x7fffffff;
    __shared__ float rsum[4];
    for (int s = 0; s < n; ++s) {
        int c = cand[s];
        float4 w4 = *(const float4*)&Wout[(size_t)c * HD + tid * 4];
        float p = dot4(h4, w4, 0.0f);
        #pragma unroll
        for (int off = 32; off; off >>= 1) p += __shfl_xor(p, off);
        if ((tid & 63) == 0) rsum[wv] = p;
        __syncthreads();
        float tot = rsum[0] + rsum[1] + rsum[2] + rsum[3] + bout[c];
        if (tot > best || (tot == best && c < bestc)) { best = tot; bestc = c; }
        __syncthreads();
    }
    if (tid == 0) resps[b * TSTEPS + t] = bestc;
    xt4[tid * NB + b] = *(const float4*)&emb[(size_t)bestc * HD + tid * 4];
}

// ---- fp32 GEMV core for gates (proven R7 path, exact) ----
template<int NPAIR>
__device__ __forceinline__ void gemv_core(const float* __restrict__ wb,
                                          const float4* __restrict__ t4,
                                          int bl, float acc0[8], float acc1[8])
{
    float4 wc[8], wn[8], h0c, h1c, h0n, h1n;
    #pragma unroll
    for (int r = 0; r < 8; ++r) wc[r] = *(const float4*)&wb[(size_t)r * HD];
    h0c = t4[bl]; h1c = t4[bl + 32];

    #pragma unroll 1
    for (int p = 0; p < NPAIR - 1; ++p) {
        const float*  w1 = wb + (2 * p + 1) * 4;
        const float4* t1 = t4 + (size_t)(2 * p + 1) * NB;
        #pragma unroll
        for (int r = 0; r < 8; ++r) wn[r] = *(const float4*)&w1[(size_t)r * HD];
        h0n = t1[bl]; h1n = t1[bl + 32];
        #pragma unroll
        for (int r = 0; r < 8; ++r) {
            acc0[r] = dot4(h0c, wc[r], acc0[r]);
            acc1[r] = dot4(h1c, wc[r], acc1[r]);
        }
        const float*  w2 = wb + (2 * p + 2) * 4;
        const float4* t2 = t4 + (size_t)(2 * p + 2) * NB;
        #pragma unroll
        for (int r = 0; r < 8; ++r) wc[r] = *(const float4*)&w2[(size_t)r * HD];
        h0c = t2[bl]; h1c = t2[bl + 32];
        #pragma unroll
        for (int r = 0; r < 8; ++r) {
            acc0[r] = dot4(h0n, wn[r], acc0[r]);
            acc1[r] = dot4(h1n, wn[r], acc1[r]);
        }
    }
    const float*  w1 = wb + (2 * NPAIR - 1) * 4;
    const float4* t1 = t4 + (size_t)(2 * NPAIR - 1) * NB;
    #pragma unroll
    for (int r = 0; r < 8; ++r) wn[r] = *(const float4*)&w1[(size_t)r * HD];
    h0n = t1[bl]; h1n = t1[bl + 32];
    #pragma unroll
    for (int r = 0; r < 8; ++r) {
        acc0[r] = dot4(h0c, wc[r], acc0[r]);
        acc1[r] = dot4(h1c, wc[r], acc1[r]);
    }
    #pragma unroll
    for (int r = 0; r < 8; ++r) {
        acc0[r] = dot4(h0n, wn[r], acc0[r]);
        acc1[r] = dot4(h1n, wn[r], acc1[r]);
    }
}

// ---------------- gates GEMV, K-split 4, gpart[ks][b][6144] ----------------
__global__ __launch_bounds__(256) void gates_gemv(
    const float4* __restrict__ xt4, const float4* __restrict__ ht4,
    const float* __restrict__ Wih, const float* __restrict__ Whh,
    float* __restrict__ gpart)
{
    int cg = blockIdx.x >> 2;
    int ks = blockIdx.x & 3;
    int tid = threadIdx.x, wid = tid >> 6, lane = tid & 63;
    int bl = lane & 31, ch = lane >> 5;
    int c0 = cg * 64 + wid * 16 + ch * 8;
    bool isH = c0 >= H3;
    const float4* __restrict__ t4 = (isH ? ht4 : xt4) + (size_t)ks * 64 * NB;
    const float* __restrict__ W   = isH ? Whh : Wih;
    const float* __restrict__ wb  = W + (size_t)(c0 - (isH ? H3 : 0)) * HD + ks * 256;

    float acc0[8] = {}, acc1[8] = {};
    gemv_core<32>(wb, t4, bl, acc0, acc1);

    float* g0 = gpart + (size_t)(ks * NB + bl) * NC6 + c0;
    float* g1 = gpart + (size_t)(ks * NB + bl + 32) * NC6 + c0;
    *(float4*)(g0)     = make_float4(acc0[0], acc0[1], acc0[2], acc0[3]);
    *(float4*)(g0 + 4) = make_float4(acc0[4], acc0[5], acc0[6], acc0[7]);
    *(float4*)(g1)     = make_float4(acc1[0], acc1[1], acc1[2], acc1[3]);
    *(float4*)(g1 + 4) = make_float4(acc1[4], acc1[5], acc1[6], acc1[7]);
}

// ---------------- GRU gate fusion: ht4 = (1-z)*n + z*ht4 ----------------
__global__ __launch_bounds__(256) void gru_fuse(
    const float* __restrict__ gpart,
    const float* __restrict__ bih, const float* __restrict__ bhh,
    float4* __restrict__ ht4)
{
    int b = blockIdx.x;
    int kg = threadIdx.x;
    int j0 = kg * 4;
    float4 ir = {}, iz = {}, in_ = {}, hr = {}, hz = {}, hn = {};
    #pragma unroll
    for (int ks = 0; ks < GKS; ++ks) {
        const float* g = gpart + (size_t)(ks * NB + b) * NC6;
        float4 a;
        a = *(const float4*)&g[j0];             ir.x+=a.x; ir.y+=a.y; ir.z+=a.z; ir.w+=a.w;
        a = *(const float4*)&g[HD + j0];        iz.x+=a.x; iz.y+=a.y; iz.z+=a.z; iz.w+=a.w;
        a = *(const float4*)&g[2*HD + j0];      in_.x+=a.x; in_.y+=a.y; in_.z+=a.z; in_.w+=a.w;
        a = *(const float4*)&g[H3 + j0];        hr.x+=a.x; hr.y+=a.y; hr.z+=a.z; hr.w+=a.w;
        a = *(const float4*)&g[H3 + HD + j0];   hz.x+=a.x; hz.y+=a.y; hz.z+=a.z; hz.w+=a.w;
        a = *(const float4*)&g[H3 + 2*HD + j0]; hn.x+=a.x; hn.y+=a.y; hn.z+=a.z; hn.w+=a.w;
    }
    float4 vbi0 = *(const float4*)&bih[j0];
    float4 vbi1 = *(const float4*)&bih[HD + j0];
    float4 vbi2 = *(const float4*)&bih[2*HD + j0];
    float4 vbh0 = *(const float4*)&bhh[j0];
    float4 vbh1 = *(const float4*)&bhh[HD + j0];
    float4 vbh2 = *(const float4*)&bhh[2*HD + j0];
    float4 hv = ht4[kg * NB + b];
    float irv[4] = {ir.x+vbi0.x, ir.y+vbi0.y, ir.z+vbi0.z, ir.w+vbi0.w};
    float izv[4] = {iz.x+vbi1.x, iz.y+vbi1.y, iz.z+vbi1.z, iz.w+vbi1.w};
    float inv[4] = {in_.x+vbi2.x, in_.y+vbi2.y, in_.z+vbi2.z, in_.w+vbi2.w};
    float hrv[4] = {hr.x+vbh0.x, hr.y+vbh0.y, hr.z+vbh0.z, hr.w+vbh0.w};
    float hzv[4] = {hz.x+vbh1.x, hz.y+vbh1.y, hz.z+vbh1.z, hz.w+vbh1.w};
    float hnv[4] = {hn.x+vbh2.x, hn.y+vbh2.y, hn.z+vbh2.z, hn.w+vbh2.w};
    float hvv[4] = {hv.x, hv.y, hv.z, hv.w};
    float o[4];
    #pragma unroll
    for (int u = 0; u < 4; ++u) {
        float r = sigmoidf_(irv[u] + hrv[u]);
        float z = sigmoidf_(izv[u] + hzv[u]);
        float n = tanhf(inv[u] + r * hnv[u]);
        o[u] = (1.0f - z) * n + z * hvv[u];
    }
    ht4[kg * NB + b] = make_float4(o[0], o[1], o[2], o[3]);
}

// ================= fallback fp32 logits path (R7, used only if ws too small) =================
__global__ __launch_bounds__(256) void logits_gemv(
    const float4* __restrict__ ht4, const float* __restrict__ Wout,
    const float* __restrict__ bout,
    float* __restrict__ bval, int* __restrict__ bidx)
{
    int tid = threadIdx.x, wid = tid >> 6, lane = tid & 63;
    int bl = lane & 31, ch = lane >> 5;
    int c0 = blockIdx.x * 64 + wid * 16 + ch * 8;
    const float* __restrict__ wb = Wout + (size_t)c0 * HD;

    float acc0[8] = {}, acc1[8] = {};
    gemv_core<128>(wb, ht4, bl, acc0, acc1);

    float bv0 = -FLT_MAX, bv1 = -FLT_MAX; int bi0 = 0, bi1 = 0;
    #pragma unroll
    for (int r = 0; r < 8; ++r) {
        float bo = bout[c0 + r];
        float v0 = acc0[r] + bo;
        float v1 = acc1[r] + bo;
        if (v0 > bv0) { bv0 = v0; bi0 = c0 + r; }
        if (v1 > bv1) { bv1 = v1; bi1 = c0 + r; }
    }
    __shared__ float sv[NB][8];
    __shared__ int   si[NB][8];
    int slot = wid * 2 + ch;
    sv[bl][slot] = bv0;      si[bl][slot] = bi0;
    sv[bl + 32][slot] = bv1; si[bl + 32][slot] = bi1;
    __syncthreads();
    if (wid == 0) {
        float bv = sv[lane][0]; int bi = si[lane][0];
        #pragma unroll
        for (int s = 1; s < 8; ++s) {
            float v = sv[lane][s];
            if (v > bv) { bv = v; bi = si[lane][s]; }
        }
        bval[(size_t)lane * LBLK + blockIdx.x] = bv;
        bidx[(size_t)lane * LBLK + blockIdx.x] = bi;
    }
}

__global__ __launch_bounds__(512) void argmax_reduce_gather(
    const float* __restrict__ bval, const int* __restrict__ bidx,
    const float* __restrict__ emb, int* __restrict__ resps, int t,
    float4* __restrict__ xt4)
{
    int b = blockIdx.x;
    int tid = threadIdx.x;
    float bv = -FLT_MAX; int bi = 0x7fffffff;
    if (tid < LBLK) { bv = bval[(size_t)b * LBLK + tid]; bi = bidx[(size_t)b * LBLK + tid]; }
    for (int off = 32; off > 0; off >>= 1) {
        float ov = __shfl_down(bv, off);
        int   oi = __shfl_down(bi, off);
        if (ov > bv || (ov == bv && oi < bi)) { bv = ov; bi = oi; }
    }
    __shared__ float sv[8];
    __shared__ int   si[8];
    __shared__ int   stok;
    int wid = tid >> 6;
    if ((tid & 63) == 0) { sv[wid] = bv; si[wid] = bi; }
    __syncthreads();
    if (tid == 0) {
        bv = sv[0]; bi = si[0];
        #pragma unroll
        for (int w = 1; w < 8; ++w)
            if (sv[w] > bv || (sv[w] == bv && si[w] < bi)) { bv = sv[w]; bi = si[w]; }
        stok = bi;
        resps[b * TSTEPS + t] = bi;
    }
    __syncthreads();
    if (tid < 256) {
        int tok = stok;
        xt4[tid * NB + b] = *(const float4*)&emb[(size_t)tok * HD + tid * 4];
    }
}

// ---------------- resp_lens ----------------
__global__ void resp_lens_kernel(const int* __restrict__ resps, int* __restrict__ lens)
{
    int b = threadIdx.x;
    if (b >= NB) return;
    int len = TSTEPS + 1;
    for (int t = TSTEPS - 1; t >= 0; t--)
        if (resps[b * TSTEPS + t] == 2) len = t + 1;
    lens[b] = len;
}

extern "C" void kernel_launch(void* const* d_in, const int* in_sizes, int n_in,
                              void* d_out, int out_size, void* d_ws, size_t ws_size,
                              hipStream_t stream) {
    const float* zs   = (const float*)d_in[0];
    const float* cs   = (const float*)d_in[1];
    const float* emb  = (const float*)d_in[2];
    const float* Wih  = (const float*)d_in[3];
    const float* Whh  = (const float*)d_in[4];
    const float* bih  = (const float*)d_in[5];
    const float* bhh  = (const float*)d_in[6];
    const float* Wout = (const float*)d_in[7];
    const float* bout = (const float*)d_in[8];
    int* out = (int*)d_out;  // [64*32 resps][64 lens], int32

    char* ws = (char*)d_ws;
    float4* xt4  = (float4*)ws; ws += (size_t)256 * NB * 16;          // 256 KB
    float4* ht4  = (float4*)ws; ws += (size_t)256 * NB * 16;          // 256 KB
    float*  gpart = (float*)ws; ws += (size_t)GKS * NB * NC6 * 4;     // 6.3 MB
    float*  bval = (float*)ws;  ws += (size_t)NB * LBLK * 4;          // 128 KB
    int*    bidx = (int*)ws;    ws += (size_t)NB * LBLK * 4;          // 128 KB
    short*  Abf  = (short*)ws;  ws += (size_t)NB * HD * 2;            // 128 KB
    float*  wnorm = (float*)ws; ws += (size_t)NV * 4;                 // 128 KB
    float*  hnorm = (float*)ws; ws += 256;                            // 64 f
    float*  lb   = (float*)ws;  ws += (size_t)NB * NV * 4;            // 8.2 MB
    short*  Wbf  = (short*)ws;  ws += (size_t)NV * HD * 2;            // 65.5 MB
    size_t needed = (size_t)(ws - (char*)d_ws);
    bool use_bf16 = ws_size >= needed;

    if (use_bf16) wbf_kernel<<<NV, 256, 0, stream>>>(Wout, Wbf, wnorm);
    init_kernel<<<NB, 256, 0, stream>>>(zs, cs, emb, ht4, xt4);
    for (int t = 0; t < TSTEPS; t++) {
        gates_gemv<<<96 * GKS, 256, 0, stream>>>(xt4, ht4, Wih, Whh, gpart);
        gru_fuse<<<NB, 256, 0, stream>>>(gpart, bih, bhh, ht4);
        if (use_bf16) {
            habf_kernel<<<NB, 256, 0, stream>>>(ht4, Abf, hnorm);
            logits_lb<<<LBLK, 256, 0, stream>>>(Abf, Wbf, bout, lb);
            select_rescore<<<NB, 256, 0, stream>>>(lb, wnorm, hnorm, Wout, bout,
                                                   ht4, emb, out, t, xt4);
        } else {
            logits_gemv<<<LBLK, 256, 0, stream>>>(ht4, Wout, bout, bval, bidx);
            argmax_reduce_gather<<<NB, 512, 0, stream>>>(bval, bidx, emb, out, t, xt4);
        }
    }
    resp_lens_kernel<<<1, 64, 0, stream>>>(out, out + NB * TSTEPS);
}

// Round 11
// 3652.934 us; speedup vs baseline: 7.0855x; 1.4746x over previous
//
#include <hip/hip_runtime.h>
#include <hip/hip_bf16.h>
#include <float.h>

#define NB 64
#define HD 1024
#define H3 3072
#define NC6 6144
#define NV 32000
#define TSTEPS 32
#define LBLK 500        // logits blocks (64 cols each)
#define BML 512         // bmlow stride (>= LBLK)
#define NSLICE 8        // select2 col slices
#define GKS 4           // gates K-split
#define NKT 16          // K=1024 / 64 per staging step
#define MARGIN_COEF 0.010f
#define MARGIN_ABS  1e-3f

using bf16x8 = __attribute__((ext_vector_type(8))) short;
using f32x4  = __attribute__((ext_vector_type(4))) float;
using s16x4  = __attribute__((ext_vector_type(4))) short;

__device__ __forceinline__ float sigmoidf_(float x) {
    return 1.0f / (1.0f + expf(-x));
}
__device__ __forceinline__ float dot4(float4 h, float4 w, float a) {
    return fmaf(h.w, w.w, fmaf(h.z, w.z, fmaf(h.y, w.y, fmaf(h.x, w.x, a))));
}
__device__ __forceinline__ short bf16bits(float x) {
    __hip_bfloat16 b = __float2bfloat16(x);
    return __builtin_bit_cast(short, b);
}
__device__ __forceinline__ unsigned ordbits(float v) {
    unsigned u = __float_as_uint(v);
    return (u & 0x80000000u) ? ~u : (u | 0x80000000u);
}

// ---------------- one-time: Wout -> Wbf (bf16) + wnorm ----------------
__global__ __launch_bounds__(256) void wbf_kernel(const float* __restrict__ W,
                                                  short* __restrict__ Wbf,
                                                  float* __restrict__ wnorm)
{
    int r = blockIdx.x, tdx = threadIdx.x;
    float4 v = *(const float4*)&W[(size_t)r * HD + tdx * 4];
    s16x4 p;
    p[0] = bf16bits(v.x); p[1] = bf16bits(v.y);
    p[2] = bf16bits(v.z); p[3] = bf16bits(v.w);
    *(s16x4*)(Wbf + (size_t)r * HD + tdx * 4) = p;
    float ss = v.x*v.x + v.y*v.y + v.z*v.z + v.w*v.w;
    #pragma unroll
    for (int off = 32; off; off >>= 1) ss += __shfl_xor(ss, off);
    __shared__ float red[4];
    if ((tdx & 63) == 0) red[tdx >> 6] = ss;
    __syncthreads();
    if (tdx == 0) wnorm[r] = sqrtf(red[0] + red[1] + red[2] + red[3]);
}

// ---------------- per-step: ht4 -> Abf (bf16 row-major) + hnorm ----------------
__global__ __launch_bounds__(256) void habf_kernel(const float4* __restrict__ ht4,
                                                   short* __restrict__ Abf,
                                                   float* __restrict__ hnorm)
{
    int b = blockIdx.x, kg = threadIdx.x;
    float4 v = ht4[kg * NB + b];
    s16x4 p;
    p[0] = bf16bits(v.x); p[1] = bf16bits(v.y);
    p[2] = bf16bits(v.z); p[3] = bf16bits(v.w);
    *(s16x4*)(Abf + (size_t)b * HD + kg * 4) = p;
    float ss = v.x*v.x + v.y*v.y + v.z*v.z + v.w*v.w;
    #pragma unroll
    for (int off = 32; off; off >>= 1) ss += __shfl_xor(ss, off);
    __shared__ float red[4];
    if ((kg & 63) == 0) red[kg >> 6] = ss;
    __syncthreads();
    if (kg == 0) hnorm[b] = sqrtf(red[0] + red[1] + red[2] + red[3]);
}

// ---------------- init: ht4 = [zs|cs]^T, xt4 = emb[SOS=1]^T ----------------
__global__ __launch_bounds__(256) void init_kernel(
    const float* __restrict__ zs, const float* __restrict__ cs,
    const float* __restrict__ emb,
    float4* __restrict__ ht4, float4* __restrict__ xt4)
{
    int b = blockIdx.x;
    int kg = threadIdx.x;
    int j = kg * 4;
    float4 v;
    if (j < 512) v = *(const float4*)&zs[b * 512 + j];
    else         v = *(const float4*)&cs[b * 512 + (j - 512)];
    ht4[kg * NB + b] = v;
    xt4[kg * NB + b] = *(const float4*)&emb[HD + j];  // SOS = 1
}

// ---------------- logits screen: bf16 MFMA GEMM -> lb + per-block lower-bound max ----------------
// 500 blocks x 256 thr (4 waves). Tile 64 batch x 64 cols, K=1024.
__global__ __launch_bounds__(256, 2) void logits_lb(
    const short* __restrict__ Abf, const short* __restrict__ Wbf,
    const float* __restrict__ bout, const float* __restrict__ wnorm,
    const float* __restrict__ hnorm,
    float* __restrict__ lb, float* __restrict__ bmlow)
{
    __shared__ __align__(16) char tile[2][16384];
    __shared__ float smax[64][4];

    const int tid = threadIdx.x;
    const int wv = tid >> 6, l = tid & 63;
    const int blk = blockIdx.x;

    const short* srows[4];
    int lof[4];
    #pragma unroll
    for (int i = 0; i < 4; ++i) {
        int slot = i * 256 + tid;
        int row = slot >> 3;
        int kb  = (slot & 7) * 16;
        const short* g = (row < 64)
            ? (Abf + (size_t)row * HD)
            : (Wbf + ((size_t)(blk * 64 + (row - 64))) * HD);
        srows[i] = g + (kb >> 1);
        lof[i] = row * 128 + (kb ^ ((row & 7) << 4));
    }

    int a_off[4][2], b_off[2];
    #pragma unroll
    for (int m = 0; m < 4; ++m)
        #pragma unroll
        for (int kf = 0; kf < 2; ++kf) {
            int row = m * 16 + (l & 15);
            int kb = kf * 64 + (l >> 4) * 16;
            a_off[m][kf] = row * 128 + (kb ^ ((row & 7) << 4));
        }
    #pragma unroll
    for (int kf = 0; kf < 2; ++kf) {
        int row = 64 + wv * 16 + (l & 15);
        int kb = kf * 64 + (l >> 4) * 16;
        b_off[kf] = row * 128 + (kb ^ ((row & 7) << 4));
    }

    float4 rg[4];
    #pragma unroll
    for (int i = 0; i < 4; ++i) rg[i] = *(const float4*)(srows[i]);

    f32x4 acc[4] = {};

    int cur = 0;
    #pragma unroll 1
    for (int kt = 0; kt < NKT; ++kt) {
        char* buf = tile[cur];
        #pragma unroll
        for (int i = 0; i < 4; ++i) *(float4*)(buf + lof[i]) = rg[i];
        __syncthreads();
        if (kt < NKT - 1) {
            #pragma unroll
            for (int i = 0; i < 4; ++i)
                rg[i] = *(const float4*)(srows[i] + (size_t)(kt + 1) * 64);
        }
        #pragma unroll
        for (int kf = 0; kf < 2; ++kf) {
            bf16x8 bfrag = *(const bf16x8*)(buf + b_off[kf]);
            #pragma unroll
            for (int m = 0; m < 4; ++m) {
                bf16x8 afrag = *(const bf16x8*)(buf + a_off[m][kf]);
                acc[m] = __builtin_amdgcn_mfma_f32_16x16x32_bf16(afrag, bfrag, acc[m], 0, 0, 0);
            }
        }
        cur ^= 1;
        __syncthreads();
    }

    // epilogue: store lb; per-block max over 64 cols of (lb - margin) per batch row
    int col = blk * 64 + wv * 16 + (l & 15);
    float bo = bout[col];
    float wn = wnorm[col];
    float selmax = -FLT_MAX;
    int pick = l & 15;
    #pragma unroll
    for (int m = 0; m < 4; ++m) {
        #pragma unroll
        for (int j = 0; j < 4; ++j) {
            int row = m * 16 + (l >> 4) * 4 + j;
            float lbv = acc[m][j] + bo;
            lb[(size_t)row * NV + col] = lbv;
            float low = lbv - (MARGIN_COEF * hnorm[row] * wn + MARGIN_ABS);
            #pragma unroll
            for (int mask = 1; mask <= 8; mask <<= 1)
                low = fmaxf(low, __shfl_xor(low, mask, 64));
            if (pick == m * 4 + j) selmax = low;
        }
    }
    int row = ((l & 15) >> 2) * 16 + (l >> 4) * 4 + (l & 3);
    smax[row][wv] = selmax;
    __syncthreads();
    if (wv == 0) {
        float v = fmaxf(fmaxf(smax[l][0], smax[l][1]), fmaxf(smax[l][2], smax[l][3]));
        bmlow[(size_t)l * BML + blk] = v;
    }
}

// ---------------- T[b] = max over blocks of bmlow; reset best ----------------
__global__ __launch_bounds__(512) void tmax_kernel(const float* __restrict__ bmlow,
                                                   float* __restrict__ T,
                                                   unsigned long long* __restrict__ best)
{
    int b = blockIdx.x, tid = threadIdx.x;
    float v = (tid < LBLK) ? bmlow[(size_t)b * BML + tid] : -FLT_MAX;
    #pragma unroll
    for (int off = 32; off; off >>= 1) v = fmaxf(v, __shfl_xor(v, off));
    __shared__ float red[8];
    if ((tid & 63) == 0) red[tid >> 6] = v;
    __syncthreads();
    if (tid == 0) {
        float m = red[0];
        #pragma unroll
        for (int w = 1; w < 8; ++w) m = fmaxf(m, red[w]);
        T[b] = m;
        best[b] = 0ull;
    }
}

// ---------------- select candidates + exact fp32 rescore + atomic commit ----------------
// grid 64*NSLICE blocks: b = blk>>3, slice = blk&7 (4000 cols each). 256 thr.
__global__ __launch_bounds__(256) void select2_kernel(
    const float* __restrict__ lb, const float* __restrict__ wnorm,
    const float* __restrict__ hnorm, const float* __restrict__ T,
    const float* __restrict__ Wout, const float* __restrict__ bout,
    const float4* __restrict__ ht4,
    unsigned long long* __restrict__ best)
{
    int b = blockIdx.x >> 3, slice = blockIdx.x & 7;
    int tid = threadIdx.x, wv = tid >> 6;
    const float* lbr = lb + (size_t)b * NV;
    float coef = MARGIN_COEF * hnorm[b];
    float tb = T[b];

    __shared__ int scount;
    __shared__ int cand[256];
    if (tid == 0) scount = 0;
    __syncthreads();

    int c0 = slice * (NV / NSLICE);
    for (int c = c0 + tid; c < c0 + NV / NSLICE; c += 256) {
        if (lbr[c] + (coef * wnorm[c] + MARGIN_ABS) >= tb) {
            int s = atomicAdd(&scount, 1);
            if (s < 256) cand[s] = c;
        }
    }
    __syncthreads();
    int n = scount < 256 ? scount : 256;
    if (n == 0) return;

    float4 h4 = ht4[tid * NB + b];
    __shared__ float rsum[4];
    for (int s = 0; s < n; ++s) {
        int c = cand[s];
        float4 w4 = *(const float4*)&Wout[(size_t)c * HD + tid * 4];
        float p = dot4(h4, w4, 0.0f);
        #pragma unroll
        for (int off = 32; off; off >>= 1) p += __shfl_xor(p, off);
        if ((tid & 63) == 0) rsum[wv] = p;
        __syncthreads();
        if (tid == 0) {
            float tot = rsum[0] + rsum[1] + rsum[2] + rsum[3] + bout[c];
            unsigned long long key =
                ((unsigned long long)ordbits(tot) << 32) | (unsigned)(~c);
            atomicMax(&best[b], key);
        }
        __syncthreads();
    }
}

// ---------------- gather winner: resps + xt4 ----------------
__global__ __launch_bounds__(256) void gather_kernel(
    const unsigned long long* __restrict__ best,
    const float* __restrict__ emb, int* __restrict__ resps, int t,
    float4* __restrict__ xt4)
{
    int b = blockIdx.x, tid = threadIdx.x;
    int c = ~(unsigned)(best[b] & 0xFFFFFFFFull);
    if (tid == 0) resps[b * TSTEPS + t] = c;
    xt4[tid * NB + b] = *(const float4*)&emb[(size_t)c * HD + tid * 4];
}

// ---- fp32 GEMV core for gates (proven R7 path, exact) ----
template<int NPAIR>
__device__ __forceinline__ void gemv_core(const float* __restrict__ wb,
                                          const float4* __restrict__ t4,
                                          int bl, float acc0[8], float acc1[8])
{
    float4 wc[8], wn[8], h0c, h1c, h0n, h1n;
    #pragma unroll
    for (int r = 0; r < 8; ++r) wc[r] = *(const float4*)&wb[(size_t)r * HD];
    h0c = t4[bl]; h1c = t4[bl + 32];

    #pragma unroll 1
    for (int p = 0; p < NPAIR - 1; ++p) {
        const float*  w1 = wb + (2 * p + 1) * 4;
        const float4* t1 = t4 + (size_t)(2 * p + 1) * NB;
        #pragma unroll
        for (int r = 0; r < 8; ++r) wn[r] = *(const float4*)&w1[(size_t)r * HD];
        h0n = t1[bl]; h1n = t1[bl + 32];
        #pragma unroll
        for (int r = 0; r < 8; ++r) {
            acc0[r] = dot4(h0c, wc[r], acc0[r]);
            acc1[r] = dot4(h1c, wc[r], acc1[r]);
        }
        const float*  w2 = wb + (2 * p + 2) * 4;
        const float4* t2 = t4 + (size_t)(2 * p + 2) * NB;
        #pragma unroll
        for (int r = 0; r < 8; ++r) wc[r] = *(const float4*)&w2[(size_t)r * HD];
        h0c = t2[bl]; h1c = t2[bl + 32];
        #pragma unroll
        for (int r = 0; r < 8; ++r) {
            acc0[r] = dot4(h0n, wn[r], acc0[r]);
            acc1[r] = dot4(h1n, wn[r], acc1[r]);
        }
    }
    const float*  w1 = wb + (2 * NPAIR - 1) * 4;
    const float4* t1 = t4 + (size_t)(2 * NPAIR - 1) * NB;
    #pragma unroll
    for (int r = 0; r < 8; ++r) wn[r] = *(const float4*)&w1[(size_t)r * HD];
    h0n = t1[bl]; h1n = t1[bl + 32];
    #pragma unroll
    for (int r = 0; r < 8; ++r) {
        acc0[r] = dot4(h0c, wc[r], acc0[r]);
        acc1[r] = dot4(h1c, wc[r], acc1[r]);
    }
    #pragma unroll
    for (int r = 0; r < 8; ++r) {
        acc0[r] = dot4(h0n, wn[r], acc0[r]);
        acc1[r] = dot4(h1n, wn[r], acc1[r]);
    }
}

// ---------------- gates GEMV, K-split 4, gpart[ks][b][6144] ----------------
__global__ __launch_bounds__(256) void gates_gemv(
    const float4* __restrict__ xt4, const float4* __restrict__ ht4,
    const float* __restrict__ Wih, const float* __restrict__ Whh,
    float* __restrict__ gpart)
{
    int cg = blockIdx.x >> 2;
    int ks = blockIdx.x & 3;
    int tid = threadIdx.x, wid = tid >> 6, lane = tid & 63;
    int bl = lane & 31, ch = lane >> 5;
    int c0 = cg * 64 + wid * 16 + ch * 8;
    bool isH = c0 >= H3;
    const float4* __restrict__ t4 = (isH ? ht4 : xt4) + (size_t)ks * 64 * NB;
    const float* __restrict__ W   = isH ? Whh : Wih;
    const float* __restrict__ wb  = W + (size_t)(c0 - (isH ? H3 : 0)) * HD + ks * 256;

    float acc0[8] = {}, acc1[8] = {};
    gemv_core<32>(wb, t4, bl, acc0, acc1);

    float* g0 = gpart + (size_t)(ks * NB + bl) * NC6 + c0;
    float* g1 = gpart + (size_t)(ks * NB + bl + 32) * NC6 + c0;
    *(float4*)(g0)     = make_float4(acc0[0], acc0[1], acc0[2], acc0[3]);
    *(float4*)(g0 + 4) = make_float4(acc0[4], acc0[5], acc0[6], acc0[7]);
    *(float4*)(g1)     = make_float4(acc1[0], acc1[1], acc1[2], acc1[3]);
    *(float4*)(g1 + 4) = make_float4(acc1[4], acc1[5], acc1[6], acc1[7]);
}

// ---------------- GRU gate fusion: ht4 = (1-z)*n + z*ht4 ----------------
__global__ __launch_bounds__(256) void gru_fuse(
    const float* __restrict__ gpart,
    const float* __restrict__ bih, const float* __restrict__ bhh,
    float4* __restrict__ ht4)
{
    int b = blockIdx.x;
    int kg = threadIdx.x;
    int j0 = kg * 4;
    float4 ir = {}, iz = {}, in_ = {}, hr = {}, hz = {}, hn = {};
    #pragma unroll
    for (int ks = 0; ks < GKS; ++ks) {
        const float* g = gpart + (size_t)(ks * NB + b) * NC6;
        float4 a;
        a = *(const float4*)&g[j0];             ir.x+=a.x; ir.y+=a.y; ir.z+=a.z; ir.w+=a.w;
        a = *(const float4*)&g[HD + j0];        iz.x+=a.x; iz.y+=a.y; iz.z+=a.z; iz.w+=a.w;
        a = *(const float4*)&g[2*HD + j0];      in_.x+=a.x; in_.y+=a.y; in_.z+=a.z; in_.w+=a.w;
        a = *(const float4*)&g[H3 + j0];        hr.x+=a.x; hr.y+=a.y; hr.z+=a.z; hr.w+=a.w;
        a = *(const float4*)&g[H3 + HD + j0];   hz.x+=a.x; hz.y+=a.y; hz.z+=a.z; hz.w+=a.w;
        a = *(const float4*)&g[H3 + 2*HD + j0]; hn.x+=a.x; hn.y+=a.y; hn.z+=a.z; hn.w+=a.w;
    }
    float4 vbi0 = *(const float4*)&bih[j0];
    float4 vbi1 = *(const float4*)&bih[HD + j0];
    float4 vbi2 = *(const float4*)&bih[2*HD + j0];
    float4 vbh0 = *(const float4*)&bhh[j0];
    float4 vbh1 = *(const float4*)&bhh[HD + j0];
    float4 vbh2 = *(const float4*)&bhh[2*HD + j0];
    float4 hv = ht4[kg * NB + b];
    float irv[4] = {ir.x+vbi0.x, ir.y+vbi0.y, ir.z+vbi0.z, ir.w+vbi0.w};
    float izv[4] = {iz.x+vbi1.x, iz.y+vbi1.y, iz.z+vbi1.z, iz.w+vbi1.w};
    float inv[4] = {in_.x+vbi2.x, in_.y+vbi2.y, in_.z+vbi2.z, in_.w+vbi2.w};
    float hrv[4] = {hr.x+vbh0.x, hr.y+vbh0.y, hr.z+vbh0.z, hr.w+vbh0.w};
    float hzv[4] = {hz.x+vbh1.x, hz.y+vbh1.y, hz.z+vbh1.z, hz.w+vbh1.w};
    float hnv[4] = {hn.x+vbh2.x, hn.y+vbh2.y, hn.z+vbh2.z, hn.w+vbh2.w};
    float hvv[4] = {hv.x, hv.y, hv.z, hv.w};
    float o[4];
    #pragma unroll
    for (int u = 0; u < 4; ++u) {
        float r = sigmoidf_(irv[u] + hrv[u]);
        float z = sigmoidf_(izv[u] + hzv[u]);
        float n = tanhf(inv[u] + r * hnv[u]);
        o[u] = (1.0f - z) * n + z * hvv[u];
    }
    ht4[kg * NB + b] = make_float4(o[0], o[1], o[2], o[3]);
}

// ================= fallback fp32 logits path (used only if ws too small) =================
__global__ __launch_bounds__(256) void logits_gemv(
    const float4* __restrict__ ht4, const float* __restrict__ Wout,
    const float* __restrict__ bout,
    float* __restrict__ bval, int* __restrict__ bidx)
{
    int tid = threadIdx.x, wid = tid >> 6, lane = tid & 63;
    int bl = lane & 31, ch = lane >> 5;
    int c0 = blockIdx.x * 64 + wid * 16 + ch * 8;
    const float* __restrict__ wb = Wout + (size_t)c0 * HD;

    float acc0[8] = {}, acc1[8] = {};
    gemv_core<128>(wb, ht4, bl, acc0, acc1);

    float bv0 = -FLT_MAX, bv1 = -FLT_MAX; int bi0 = 0, bi1 = 0;
    #pragma unroll
    for (int r = 0; r < 8; ++r) {
        float bo = bout[c0 + r];
        float v0 = acc0[r] + bo;
        float v1 = acc1[r] + bo;
        if (v0 > bv0) { bv0 = v0; bi0 = c0 + r; }
        if (v1 > bv1) { bv1 = v1; bi1 = c0 + r; }
    }
    __shared__ float sv[NB][8];
    __shared__ int   si[NB][8];
    int slot = wid * 2 + ch;
    sv[bl][slot] = bv0;      si[bl][slot] = bi0;
    sv[bl + 32][slot] = bv1; si[bl + 32][slot] = bi1;
    __syncthreads();
    if (wid == 0) {
        float bv = sv[lane][0]; int bi = si[lane][0];
        #pragma unroll
        for (int s = 1; s < 8; ++s) {
            float v = sv[lane][s];
            if (v > bv) { bv = v; bi = si[lane][s]; }
        }
        bval[(size_t)lane * LBLK + blockIdx.x] = bv;
        bidx[(size_t)lane * LBLK + blockIdx.x] = bi;
    }
}

__global__ __launch_bounds__(512) void argmax_reduce_gather(
    const float* __restrict__ bval, const int* __restrict__ bidx,
    const float* __restrict__ emb, int* __restrict__ resps, int t,
    float4* __restrict__ xt4)
{
    int b = blockIdx.x;
    int tid = threadIdx.x;
    float bv = -FLT_MAX; int bi = 0x7fffffff;
    if (tid < LBLK) { bv = bval[(size_t)b * LBLK + tid]; bi = bidx[(size_t)b * LBLK + tid]; }
    for (int off = 32; off > 0; off >>= 1) {
        float ov = __shfl_down(bv, off);
        int   oi = __shfl_down(bi, off);
        if (ov > bv || (ov == bv && oi < bi)) { bv = ov; bi = oi; }
    }
    __shared__ float sv[8];
    __shared__ int   si[8];
    __shared__ int   stok;
    int wid = tid >> 6;
    if ((tid & 63) == 0) { sv[wid] = bv; si[wid] = bi; }
    __syncthreads();
    if (tid == 0) {
        bv = sv[0]; bi = si[0];
        #pragma unroll
        for (int w = 1; w < 8; ++w)
            if (sv[w] > bv || (sv[w] == bv && si[w] < bi)) { bv = sv[w]; bi = si[w]; }
        stok = bi;
        resps[b * TSTEPS + t] = bi;
    }
    __syncthreads();
    if (tid < 256) {
        int tok = stok;
        xt4[tid * NB + b] = *(const float4*)&emb[(size_t)tok * HD + tid * 4];
    }
}

// ---------------- resp_lens ----------------
__global__ void resp_lens_kernel(const int* __restrict__ resps, int* __restrict__ lens)
{
    int b = threadIdx.x;
    if (b >= NB) return;
    int len = TSTEPS + 1;
    for (int t = TSTEPS - 1; t >= 0; t--)
        if (resps[b * TSTEPS + t] == 2) len = t + 1;
    lens[b] = len;
}

extern "C" void kernel_launch(void* const* d_in, const int* in_sizes, int n_in,
                              void* d_out, int out_size, void* d_ws, size_t ws_size,
                              hipStream_t stream) {
    const float* zs   = (const float*)d_in[0];
    const float* cs   = (const float*)d_in[1];
    const float* emb  = (const float*)d_in[2];
    const float* Wih  = (const float*)d_in[3];
    const float* Whh  = (const float*)d_in[4];
    const float* bih  = (const float*)d_in[5];
    const float* bhh  = (const float*)d_in[6];
    const float* Wout = (const float*)d_in[7];
    const float* bout = (const float*)d_in[8];
    int* out = (int*)d_out;  // [64*32 resps][64 lens], int32

    char* ws = (char*)d_ws;
    float4* xt4  = (float4*)ws; ws += (size_t)256 * NB * 16;          // 256 KB
    float4* ht4  = (float4*)ws; ws += (size_t)256 * NB * 16;          // 256 KB
    float*  gpart = (float*)ws; ws += (size_t)GKS * NB * NC6 * 4;     // 6.3 MB
    float*  bval = (float*)ws;  ws += (size_t)NB * LBLK * 4;          // 128 KB
    int*    bidx = (int*)ws;    ws += (size_t)NB * LBLK * 4;          // 128 KB
    short*  Abf  = (short*)ws;  ws += (size_t)NB * HD * 2;            // 128 KB
    float*  wnorm = (float*)ws; ws += (size_t)NV * 4;                 // 128 KB
    float*  hnorm = (float*)ws; ws += 256;                            // 64 f
    float*  bmlow = (float*)ws; ws += (size_t)NB * BML * 4;           // 128 KB
    float*  Tb   = (float*)ws;  ws += 256;                            // 64 f
    unsigned long long* best = (unsigned long long*)ws; ws += NB * 8; // 512 B
    float*  lb   = (float*)ws;  ws += (size_t)NB * NV * 4;            // 8.2 MB
    short*  Wbf  = (short*)ws;  ws += (size_t)NV * HD * 2;            // 65.5 MB
    size_t needed = (size_t)(ws - (char*)d_ws);
    bool use_bf16 = ws_size >= needed;

    if (use_bf16) wbf_kernel<<<NV, 256, 0, stream>>>(Wout, Wbf, wnorm);
    init_kernel<<<NB, 256, 0, stream>>>(zs, cs, emb, ht4, xt4);
    for (int t = 0; t < TSTEPS; t++) {
        gates_gemv<<<96 * GKS, 256, 0, stream>>>(xt4, ht4, Wih, Whh, gpart);
        gru_fuse<<<NB, 256, 0, stream>>>(gpart, bih, bhh, ht4);
        if (use_bf16) {
            habf_kernel<<<NB, 256, 0, stream>>>(ht4, Abf, hnorm);
            logits_lb<<<LBLK, 256, 0, stream>>>(Abf, Wbf, bout, wnorm, hnorm, lb, bmlow);
            tmax_kernel<<<NB, 512, 0, stream>>>(bmlow, Tb, best);
            select2_kernel<<<NB * NSLICE, 256, 0, stream>>>(lb, wnorm, hnorm, Tb,
                                                            Wout, bout, ht4, best);
            gather_kernel<<<NB, 256, 0, stream>>>(best, emb, out, t, xt4);
        } else {
            logits_gemv<<<LBLK, 256, 0, stream>>>(ht4, Wout, bout, bval, bidx);
            argmax_reduce_gather<<<NB, 512, 0, stream>>>(bval, bidx, emb, out, t, xt4);
        }
    }
    resp_lens_kernel<<<1, 64, 0, stream>>>(out, out + NB * TSTEPS);
}